// Round 1
// baseline (54.825 us; speedup 1.0000x reference)
//
#include <hip/hip_runtime.h>
#include <hip/hip_bf16.h>

// CTC batch cost, faithful port of the JAX reference (incl. the input_len = C
// source bug). B=512, T=512, C=128, L=64 -> S=129 states, TU=128 time steps.

#define BB 512
#define TT 512
#define CC 128
#define LL 64
#define SS 129   // 2L+1
#define TU 128   // input_len = C (source bug, replicated)
#define NEGV -1e30f
#define EPSV 1e-7f

__global__ __launch_bounds__(192) void ctc_kernel(const int* __restrict__ y_true,
                                                  const float* __restrict__ y_pred,
                                                  float* __restrict__ out) {
    const int b = blockIdx.x;
    const int s = threadIdx.x;

    __shared__ float alpha[2][SS + 1];

    const float* yp = y_pred + (size_t)b * TT * CC;

    // Per-thread extended label + skip_ok (computed once).
    int ext_s = CC - 1;   // blank
    bool skip = false;
    if (s < SS) {
        if (s & 1) {
            int lbl = y_true[b * LL + (s >> 1)];
            ext_s = lbl;
            if (s >= 2) {
                int prev = y_true[b * LL + ((s - 2) >> 1)];
                skip = (lbl != prev);   // ext_s != blank is guaranteed (odd s)
            }
        }
    }

    // alpha0: only states 0 and 1 initialized to lp[0, s], rest NEG.
    if (s < SS) {
        float lp0 = __logf(0.0f);  // placeholder; overwritten below
        float p = yp[0 * CC + ext_s];
        lp0 = logf(p + EPSV);
        alpha[0][s] = (s <= 1) ? lp0 : NEGV;
    }
    __syncthreads();

    int cur = 0;
    for (int t = 1; t < TU; ++t) {
        if (s < SS) {
            float a0 = alpha[cur][s];
            float a1 = (s >= 1) ? alpha[cur][s - 1] : NEGV;
            float a2 = skip ? alpha[cur][s - 2] : NEGV;
            float m = fmaxf(fmaxf(fmaxf(a0, a1), a2), NEGV);
            float sum = expf(a0 - m) + expf(a1 - m) + expf(a2 - m);
            float lp = logf(yp[t * CC + ext_s] + EPSV);
            alpha[cur ^ 1][s] = m + logf(sum) + lp;
        }
        cur ^= 1;
        __syncthreads();
    }

    if (s == 0) {
        float x = alpha[cur][SS - 2];
        float y = alpha[cur][SS - 1];
        float m = fmaxf(x, y);
        out[b] = -(m + logf(expf(x - m) + expf(y - m)));
    }
}

extern "C" void kernel_launch(void* const* d_in, const int* in_sizes, int n_in,
                              void* d_out, int out_size, void* d_ws, size_t ws_size,
                              hipStream_t stream) {
    const int*   y_true = (const int*)d_in[0];
    const float* y_pred = (const float*)d_in[1];
    float*       out    = (float*)d_out;
    (void)in_sizes; (void)n_in; (void)out_size; (void)d_ws; (void)ws_size;

    ctc_kernel<<<BB, 192, 0, stream>>>(y_true, y_pred, out);
}

// Round 3
// 24.489 us; speedup vs baseline: 2.2387x; 2.2387x over previous
//
#include <hip/hip_runtime.h>
#include <hip/hip_bf16.h>

// CTC batch cost, faithful port of the JAX reference (incl. the input_len = C
// source bug). B=512, T=512, C=128, L=64 -> S=129 states, TU=128 time steps.
//
// One 64-lane wave per batch element. Lane i owns extended states s0=2i
// (blank) and s1=2i+1 (label y_true[i]); lane 63 additionally owns s2=128
// (final blank) whose dependencies (states 127,126) are lane-local.
// Per-step cross-lane need is exactly one __shfl_up of b1 (alpha[2i-1]):
//   state 2i   (blank):  lse2(alpha[2i],   alpha[2i-1]) + lp_blank
//   state 2i+1 (label):  lse3(alpha[2i+1], alpha[2i], skip? alpha[2i-1]) + lp_lbl
//   state 128  (blank):  lse2(alpha[128],  alpha[127]) + lp_blank   (lane 63)
// Whole recursion runs in log2 space (beta = alpha/ln2) so v_exp_f32/v_log_f32
// are used directly; final loss = -ln2 * lse2_log2(tail).

#define BB 512
#define TT 512
#define CC 128
#define LL 64
#define TU 128   // input_len = C (source bug, replicated)
#define NEGF -1e30f
#define EPSF 1e-7f
#define PD 8     // prefetch depth (register ring, static indices via unroll)
#define LN2F 0.69314718055994530942f

#if __has_builtin(__builtin_amdgcn_exp2f)
#define EXP2F(x) __builtin_amdgcn_exp2f(x)
#else
#define EXP2F(x) exp2f(x)
#endif
#define LOG2F(x) __log2f(x)   // HIP device fast intrinsic (v_log_f32)

__device__ __forceinline__ float lse2_log2(float a, float b) {
    float m = fmaxf(a, b);
    return m + LOG2F(EXP2F(a - m) + EXP2F(b - m));
}

__global__ __launch_bounds__(64) void ctc_wave(const int* __restrict__ y_true,
                                               const float* __restrict__ y_pred,
                                               float* __restrict__ out) {
    const int b = blockIdx.x;
    const int lane = threadIdx.x;
    const float* yp = y_pred + (size_t)b * TT * CC;

    const int lbl  = y_true[b * LL + lane];   // label for state 2*lane+1
    const int lblp = __shfl_up(lbl, 1);
    const bool skip = (lane >= 1) && (lbl != lblp);

    // t = 0 init: only states 0 and 1 start at lp[0,s]; everything else NEG.
    const float lp2b0 = LOG2F(yp[CC - 1] + EPSF);
    const float lp2l0 = LOG2F(yp[lbl] + EPSF);
    float b0 = (lane == 0) ? lp2b0 : NEGF;   // state 2*lane (blank)
    float b1 = (lane == 0) ? lp2l0 : NEGF;   // state 2*lane+1 (label)
    float b2 = NEGF;                          // state 128 (valid in lane 63)

    // Prefetch ring for t = 1..PD. (Loads past t=127 read rows <= 135 < 512 of
    // this batch's slab -- in-bounds, values never consumed.)
    float pl[PD], pb[PD];
#pragma unroll
    for (int j = 0; j < PD; ++j) {
        pl[j] = yp[(1 + j) * CC + lbl];
        pb[j] = yp[(1 + j) * CC + (CC - 1)];
    }

    for (int tb = 1; tb < TU; tb += PD) {
#pragma unroll
        for (int j = 0; j < PD; ++j) {
            const int t = tb + j;
            const float plv = pl[j];
            const float pbv = pb[j];
            // refill slot j for iteration t+PD
            pl[j] = yp[(t + PD) * CC + lbl];
            pb[j] = yp[(t + PD) * CC + (CC - 1)];
            if (t < TU) {
                const float lpl = LOG2F(plv + EPSF);
                const float lpb = LOG2F(pbv + EPSF);
                float b1p = __shfl_up(b1, 1);
                b1p = (lane == 0) ? NEGF : b1p;
                // state 2i (blank)
                const float nb0 = lse2_log2(b0, b1p) + lpb;
                // state 2i+1 (label)
                const float a2 = skip ? b1p : NEGF;
                const float m  = fmaxf(fmaxf(b1, b0), a2);
                const float nb1 = m + LOG2F(EXP2F(b1 - m) + EXP2F(b0 - m)
                                            + EXP2F(a2 - m)) + lpl;
                // state 128 (blank; lane-63 local)
                const float nb2 = lse2_log2(b2, b1) + lpb;
                b0 = nb0; b1 = nb1; b2 = nb2;
            }
        }
    }

    if (lane == 63) {
        out[b] = -LN2F * lse2_log2(b1, b2);   // tail = states 127, 128
    }
}

extern "C" void kernel_launch(void* const* d_in, const int* in_sizes, int n_in,
                              void* d_out, int out_size, void* d_ws, size_t ws_size,
                              hipStream_t stream) {
    const int*   y_true = (const int*)d_in[0];
    const float* y_pred = (const float*)d_in[1];
    float*       out    = (float*)d_out;
    (void)in_sizes; (void)n_in; (void)out_size; (void)d_ws; (void)ws_size;

    ctc_wave<<<BB, 64, 0, stream>>>(y_true, y_pred, out);
}

// Round 4
// 21.622 us; speedup vs baseline: 2.5356x; 1.1326x over previous
//
#include <hip/hip_runtime.h>
#include <hip/hip_bf16.h>

// CTC batch cost, faithful port of the JAX reference (incl. the input_len = C
// source bug). B=512, T=512, C=128, L=64 -> S=129 states, TU=128 time steps.
//
// One 64-lane wave per batch element. Lane i owns extended states s0=2i
// (blank) and s1=2i+1 (label y_true[i]); lane 63 additionally owns s2=128.
// Per-step cross-lane need is one shift-up-by-1 of b1 (alpha[2i-1]), done
// with DPP (row_shr:1 + row_bcast15 for lanes 16/32/48) instead of
// ds_bpermute -- keeps the ~120-cyc DS latency off the serial chain.
// Whole recursion runs in log2 space; loss = -ln2 * lse2_log2(tail).

#define BB 512
#define TT 512
#define CC 128
#define LL 64
#define TU 128   // input_len = C (source bug, replicated)
#define NEGF -1e30f
#define EPSF 1e-7f
#define PD 16    // prefetch depth (register ring, static indices via unroll)
#define LN2F 0.69314718055994530942f

#if __has_builtin(__builtin_amdgcn_exp2f)
#define EXP2F(x) __builtin_amdgcn_exp2f(x)
#else
#define EXP2F(x) exp2f(x)
#endif
#define LOG2F(x) __log2f(x)   // HIP device fast intrinsic (v_log_f32)

__device__ __forceinline__ float lse2_log2(float a, float b) {
    float m = fmaxf(a, b);
    return m + LOG2F(EXP2F(a - m) + EXP2F(b - m));
}

// value of lane-1's x; NEGF into lane 0. DPP only (no LDS on the chain).
__device__ __forceinline__ float shift_up1(float x, int lane) {
    const int xi = __float_as_int(x);
    // row_shr:1 -- lane l <- lane l-1 within each 16-lane row
    const int sh = __builtin_amdgcn_update_dpp(xi, xi, 0x111, 0xF, 0xF, false);
    // row_bcast15 -- each row's lane 15 broadcast into the next row
    const int bc = __builtin_amdgcn_update_dpp(xi, xi, 0x142, 0xF, 0xF, false);
    float r = ((lane & 15) == 0) ? __int_as_float(bc) : __int_as_float(sh);
    return (lane == 0) ? NEGF : r;
}

__global__ __launch_bounds__(64) void ctc_wave(const int* __restrict__ y_true,
                                               const float* __restrict__ y_pred,
                                               float* __restrict__ out) {
    const int b = blockIdx.x;
    const int lane = threadIdx.x;
    const float* yp = y_pred + (size_t)b * TT * CC;

    const int lbl  = y_true[b * LL + lane];   // label for state 2*lane+1
    const int lblp = __shfl_up(lbl, 1);       // one-time, off the hot loop
    const bool skip = (lane >= 1) && (lbl != lblp);

    // t = 0 init: only states 0 and 1 start at lp[0,s]; everything else NEG.
    const float lp2b0 = LOG2F(yp[CC - 1] + EPSF);
    const float lp2l0 = LOG2F(yp[lbl] + EPSF);
    float b0 = (lane == 0) ? lp2b0 : NEGF;   // state 2*lane (blank)
    float b1 = (lane == 0) ? lp2l0 : NEGF;   // state 2*lane+1 (label)
    float b2 = NEGF;                          // state 128 (valid in lane 63)

    // Prefetch ring for t = 1..PD. (Loads past t=127 read rows <= 144 < 512 of
    // this batch's slab -- in-bounds, values never consumed.)
    float pl[PD], pb[PD];
#pragma unroll
    for (int j = 0; j < PD; ++j) {
        pl[j] = yp[(1 + j) * CC + lbl];
        pb[j] = yp[(1 + j) * CC + (CC - 1)];
    }

    for (int tb = 1; tb < TU; tb += PD) {
#pragma unroll
        for (int j = 0; j < PD; ++j) {
            const int t = tb + j;
            const float plv = pl[j];
            const float pbv = pb[j];
            // refill slot j for iteration t+PD
            pl[j] = yp[(t + PD) * CC + lbl];
            pb[j] = yp[(t + PD) * CC + (CC - 1)];
            if (t < TU) {
                const float lpl = LOG2F(plv + EPSF);
                const float lpb = LOG2F(pbv + EPSF);
                const float b1p = shift_up1(b1, lane);
                // state 2i (blank)
                const float nb0 = lse2_log2(b0, b1p) + lpb;
                // state 2i+1 (label)
                const float a2 = skip ? b1p : NEGF;
                const float m  = fmaxf(fmaxf(b1, b0), a2);
                const float nb1 = m + LOG2F(EXP2F(b1 - m) + EXP2F(b0 - m)
                                            + EXP2F(a2 - m)) + lpl;
                // state 128 (blank; lane-63 local)
                const float nb2 = lse2_log2(b2, b1) + lpb;
                b0 = nb0; b1 = nb1; b2 = nb2;
            }
        }
    }

    if (lane == 63) {
        out[b] = -LN2F * lse2_log2(b1, b2);   // tail = states 127, 128
    }
}

extern "C" void kernel_launch(void* const* d_in, const int* in_sizes, int n_in,
                              void* d_out, int out_size, void* d_ws, size_t ws_size,
                              hipStream_t stream) {
    const int*   y_true = (const int*)d_in[0];
    const float* y_pred = (const float*)d_in[1];
    float*       out    = (float*)d_out;
    (void)in_sizes; (void)n_in; (void)out_size; (void)d_ws; (void)ws_size;

    ctc_wave<<<BB, 64, 0, stream>>>(y_true, y_pred, out);
}

// Round 6
// 14.861 us; speedup vs baseline: 3.6891x; 1.4549x over previous
//
#include <hip/hip_runtime.h>
#include <hip/hip_bf16.h>

// CTC batch cost, faithful port of the JAX reference (incl. the input_len = C
// source bug). B=512, T=512, C=128, L=64 -> S=129 states, TU=128 time steps.
//
// One 64-lane wave per batch element; lane i owns states 2i (blank, b0) and
// 2i+1 (label, b1); lane 63 also owns state 128 (b2). Recursion runs in
// SCALED LINEAR space (no transcendentals on the serial chain):
//   nb0 = (b0 + b1p) * pb,  nb1 = (b0 + b1 + skip*b1p) * pl,
//   nb2 = (b2 + b1) * pb        (b1p = lane-1's b1, via DPP)
// Every 8 steps: renormalize by the wave max (DPP butterfly, no LDS) using an
// exact power-of-two scale (frexp exponent), accumulate exponent in an int.
// Relevance mask (lane+64 >= t_done) keeps the max tracking states that can
// still reach the tail. loss = -ln2 * (log2(b1+b2) + acc)  at lane 63.
// Softmax data (128 classes) guarantees 3*p < 0.5 -> always decays, no
// overflow; per-8-step decay ~2^-56 -> flushed lanes are >=2^-70 relative,
// negligible and regenerated from neighbor inflow next step.

#define BB 512
#define TT 512
#define CC 128
#define LL 64
#define TU 128   // input_len = C (source bug, replicated)
#define EPSF 1e-7f
#define PD 16    // prefetch depth (register ring, static indices via unroll)
#define LN2F 0.69314718055994530942f

template <int CTRL>
__device__ __forceinline__ float dpp_f(float x) {
    const int xi = __float_as_int(x);
    return __int_as_float(__builtin_amdgcn_update_dpp(xi, xi, CTRL, 0xF, 0xF, false));
}

// lane-1's x; 0.0 into lane 0 (linear-space 'NEG'). DPP only, no LDS.
__device__ __forceinline__ float shift_up1z(float x, int lane) {
    const int xi = __float_as_int(x);
    const int sh = __builtin_amdgcn_update_dpp(xi, xi, 0x111, 0xF, 0xF, false); // row_shr:1
    const int bc = __builtin_amdgcn_update_dpp(xi, xi, 0x142, 0xF, 0xF, false); // row_bcast15
    float r = ((lane & 15) == 0) ? __int_as_float(bc) : __int_as_float(sh);
    return (lane == 0) ? 0.0f : r;
}

// wave-wide max via DPP butterfly (quad_perm pairs/quads, half/row mirror,
// row_bcast15/31); global max lands in lane 63, broadcast via readlane.
__device__ __forceinline__ float wave_max(float v) {
    v = fmaxf(v, dpp_f<0xB1>(v));   // quad_perm [1,0,3,2]
    v = fmaxf(v, dpp_f<0x4E>(v));   // quad_perm [2,3,0,1]
    v = fmaxf(v, dpp_f<0x141>(v));  // row_half_mirror
    v = fmaxf(v, dpp_f<0x140>(v));  // row_mirror -> row max everywhere
    v = fmaxf(v, dpp_f<0x142>(v));  // row_bcast15
    v = fmaxf(v, dpp_f<0x143>(v));  // row_bcast31 -> global max in lane 63
    return __int_as_float(__builtin_amdgcn_readlane(__float_as_int(v), 63));
}

__device__ __forceinline__ void renorm(float& b0, float& b1, float& b2,
                                       int& acc, int lane, int t_done) {
    float m = fmaxf(b0, b1);
    if (lane == 63) m = fmaxf(m, b2);
    // only lanes that can still reach the tail states matter
    m = (lane + 64 >= t_done) ? m : 0.0f;
    const float M = wave_max(m);
    int e = 0;
    (void)frexpf(M, &e);                 // M = f * 2^e ; frexpf(0) -> e=0
    const float scale = ldexpf(1.0f, -e);  // exact power of two
    b0 *= scale; b1 *= scale; b2 *= scale;
    acc += e;
}

__global__ __launch_bounds__(64) void ctc_wave(const int* __restrict__ y_true,
                                               const float* __restrict__ y_pred,
                                               float* __restrict__ out) {
    const int b = blockIdx.x;
    const int lane = threadIdx.x;
    const float* yp = y_pred + (size_t)b * TT * CC;

    const int lbl  = y_true[b * LL + lane];   // label for state 2*lane+1
    const int lblp = __shfl_up(lbl, 1);       // one-time, off the hot loop
    const bool skip = (lane >= 1) && (lbl != lblp);

    // t = 0 init (linear space): states 0,1 = p + eps; everything else 0.
    float b0 = (lane == 0) ? (yp[CC - 1] + EPSF) : 0.0f;
    float b1 = (lane == 0) ? (yp[lbl] + EPSF) : 0.0f;
    float b2 = 0.0f;
    int acc = 0;

    // Prefetch ring for t = 1..PD. (Loads past t=127 read rows <= 143 < 512 of
    // this batch's slab -- in-bounds, values never consumed.)
    float pl[PD], pb[PD];
#pragma unroll
    for (int j = 0; j < PD; ++j) {
        pl[j] = yp[(1 + j) * CC + lbl];
        pb[j] = yp[(1 + j) * CC + (CC - 1)];
    }

    for (int tb = 1; tb < TU; tb += PD) {
#pragma unroll
        for (int j = 0; j < PD; ++j) {
            const int t = tb + j;
            const float plv = pl[j];
            const float pbv = pb[j];
            // refill slot j for iteration t+PD
            pl[j] = yp[(t + PD) * CC + lbl];
            pb[j] = yp[(t + PD) * CC + (CC - 1)];
            if (t < TU) {
                const float pbe = pbv + EPSF;
                const float ple = plv + EPSF;
                const float b1p = shift_up1z(b1, lane);
                const float nb0 = (b0 + b1p) * pbe;
                const float s1  = b0 + b1 + (skip ? b1p : 0.0f);
                const float nb1 = s1 * ple;
                const float nb2 = (b2 + b1) * pbe;
                b0 = nb0; b1 = nb1; b2 = nb2;
            }
            if ((j & 7) == 7) renorm(b0, b1, b2, acc, lane, tb + j);
        }
    }

    if (lane == 63) {
        const float s = b1 + b2;             // states 127, 128
        out[b] = -LN2F * (__log2f(s) + (float)acc);
    }
}

extern "C" void kernel_launch(void* const* d_in, const int* in_sizes, int n_in,
                              void* d_out, int out_size, void* d_ws, size_t ws_size,
                              hipStream_t stream) {
    const int*   y_true = (const int*)d_in[0];
    const float* y_pred = (const float*)d_in[1];
    float*       out    = (float*)d_out;
    (void)in_sizes; (void)n_in; (void)out_size; (void)d_ws; (void)ws_size;

    ctc_wave<<<BB, 64, 0, stream>>>(y_true, y_pred, out);
}